// Round 6
// baseline (1194.986 us; speedup 1.0000x reference)
//
#include <hip/hip_runtime.h>
#include <hip/hip_bf16.h>
#include <hip/hip_fp16.h>

// GroupAttention: B=4, N=8192, C=1024, H=16, Dh=64, g=4, G=2048.
//
// Evidence: round-3 (600 MiB ws, unchecked) aborted on device; index algebra
// audited clean repeatedly -> ws overrun is the surviving theory. This version
// slices M adaptively so the pipeline fits in 112 / 40 / 22 MiB of scratch,
// picked from ws_size at runtime (deterministic branch, graph-capture-safe).
// All tiers are f32-accurate (fp16 hi/lo split GEMM emulation, ~1e-4 absmax).
//
// Per slice (Ms rows, slice boundary never splits a 4-row group):
//   GEMM1: QKVs(f32) = x_s @ w_qkv   (A split to hi/lo fp16 in registers ->
//          LDS; B pre-split hi/lo; combos AhBh + AlBh + AhBl; K=1024)
//   attn:  per (b,g,h) 4x4 softmax-attention, O overwrites q-region IN PLACE
//          (each unit exclusively owns its rows x cols; reads precede writes)
//   GEMM2: out_s = O_s @ w_proj + b_proj   (A = q-region, lda=3072)
//
// ws layout (byte offsets), QKVs = Ms*3072*4 bytes:
//   QKVs @ 0
//   Bqh  @ QKVs_end            : 6291456   (w_qkv hi,  3072 x 1024 fp16)
//   Bql  @ +6291456            : 6291456   (w_qkv lo)
//   Bph  @ +12582912           : 2097152   (w_proj hi, 1024 x 1024 fp16)
//   Bpl  @ +14680064           : 2097152   (w_proj lo)
// tiers: Ms=8192 -> 117440512 B; Ms=2048 -> 41943040 B; Ms=512 -> 23068672 B.

typedef float    f32x4 __attribute__((ext_vector_type(4)));
typedef _Float16 f16x8 __attribute__((ext_vector_type(8)));
typedef _Float16 f16x4 __attribute__((ext_vector_type(4)));

__device__ __forceinline__ void gload16(const _Float16* g, _Float16* l) {
  __builtin_amdgcn_global_load_lds((const __attribute__((address_space(1))) void*)g,
                                   (__attribute__((address_space(3))) void*)l,
                                   16, 0, 0);
}

// ---------------- W (1024 x N, row-major) -> BTh/BTl (N x 1024, k-contig) ----
__global__ void wsplit_kernel(const float* __restrict__ W,
                              _Float16* __restrict__ BTh,
                              _Float16* __restrict__ BTl, int N) {
  __shared__ float tile[64][65];                 // +1 pad: conflict-free transpose
  int n0 = blockIdx.x * 64;
  int k0 = blockIdx.y * 64;
  int t  = threadIdx.x;
  int tr = t >> 4, tc = t & 15;
#pragma unroll
  for (int it = 0; it < 4; ++it) {
    int k = k0 + tr + it * 16;
    f32x4 v = *reinterpret_cast<const f32x4*>(W + (size_t)k * N + n0 + (tc << 2));
#pragma unroll
    for (int c = 0; c < 4; ++c) tile[tr + it * 16][(tc << 2) + c] = v[c];
  }
  __syncthreads();
#pragma unroll
  for (int it = 0; it < 4; ++it) {
    int n = n0 + tr + it * 16;
    f16x4 hi, lo;
#pragma unroll
    for (int c = 0; c < 4; ++c) {
      float f = tile[(tc << 2) + c][tr + it * 16];   // = W[k0+tc*4+c][n]
      _Float16 h = (_Float16)f;
      hi[c] = h;
      lo[c] = (_Float16)(f - (float)h);
    }
    size_t off = (size_t)n * 1024 + k0 + (tc << 2);
    *reinterpret_cast<f16x4*>(BTh + off) = hi;
    *reinterpret_cast<f16x4*>(BTl + off) = lo;
  }
}

// ---------------- split GEMM, K=1024 fixed --------------------------------
// A: f32 (lda), reg-staged, split hi/lo -> LDS. B: pre-split fp16 (ldb=1024).
// C: f32 (ldc) + optional bias. Combos: AhBh + AlBh + AhBl (~fp32 accuracy).
// 128x128 tile, 4 waves (2x2), 16x16x32 MFMA, 4x4 acc per wave.
__launch_bounds__(256)
__global__ void gemm_split_kernel(const float* __restrict__ A,
                                  const _Float16* __restrict__ Bh,
                                  const _Float16* __restrict__ Bl,
                                  float* __restrict__ C,
                                  const float* __restrict__ bias,
                                  int M, int N, int lda, int ldc) {
  __shared__ _Float16 lAh[128 * 32];
  __shared__ _Float16 lAl[128 * 32];
  __shared__ _Float16 lBh[128 * 32];
  __shared__ _Float16 lBl[128 * 32];

  // bijective XCD swizzle (all grids are multiples of 8)
  int nwg = gridDim.x, bid = blockIdx.x;
  int q8  = nwg >> 3;
  int swz = (bid & 7) * q8 + (bid >> 3);
  int Mt  = M >> 7;
  int tm  = swz % Mt, tn = swz / Mt;     // M-major: neighbors share the B panel
  int brow = tm << 7, bcol = tn << 7;

  int t  = threadIdx.x;
  int wv = t >> 6, lane = t & 63;
  int wrow = (wv >> 1) << 6;             // 2x2 waves, 64x64 each
  int wcol = (wv & 1) << 6;
  int lr = lane & 15, kb = lane >> 4;

  // A staging: thread t loads f32x4 at row (t>>3)+32p, k (t&7)*4; splits in reg
  const float* paf = A + (size_t)(brow + (t >> 3)) * lda + ((t & 7) << 2);
  _Float16* wAh = lAh + (t >> 3) * 32 + ((t & 7) << 2);
  _Float16* wAl = lAl + (t >> 3) * 32 + ((t & 7) << 2);

  // B staging (hi and lo), ldb = 1024; gload16 linear LDS (m104 rule)
  const _Float16* pbh0 = Bh + (size_t)(bcol + (t >> 2)) * 1024 + ((t & 3) << 3);
  const _Float16* pbh1 = pbh0 + (size_t)64 * 1024;
  const _Float16* pbl0 = Bl + (size_t)(bcol + (t >> 2)) * 1024 + ((t & 3) << 3);
  const _Float16* pbl1 = pbl0 + (size_t)64 * 1024;
  _Float16* lBh0 = lBh + wv * 512;
  _Float16* lBh1 = lBh + 2048 + wv * 512;
  _Float16* lBl0 = lBl + wv * 512;
  _Float16* lBl1 = lBl + 2048 + wv * 512;

  // fragment reads (m92 pattern: row = lane&15 (+16i), k = (lane>>4)*8)
  const _Float16* arh = lAh + (wrow + lr) * 32 + kb * 8;
  const _Float16* arl = lAl + (wrow + lr) * 32 + kb * 8;
  const _Float16* brh = lBh + (wcol + lr) * 32 + kb * 8;
  const _Float16* brl = lBl + (wcol + lr) * 32 + kb * 8;

  f32x4 acc[4][4] = {};

  for (int kt = 0; kt < 1024; kt += 32) {
#pragma unroll
    for (int p = 0; p < 4; ++p) {
      f32x4 v = *reinterpret_cast<const f32x4*>(paf + (size_t)(p * 32) * lda + kt);
      f16x4 h, l;
#pragma unroll
      for (int c = 0; c < 4; ++c) {
        _Float16 hh = (_Float16)v[c];
        h[c] = hh;
        l[c] = (_Float16)(v[c] - (float)hh);
      }
      *reinterpret_cast<f16x4*>(wAh + p * 1024) = h;
      *reinterpret_cast<f16x4*>(wAl + p * 1024) = l;
    }
    gload16(pbh0 + kt, lBh0);
    gload16(pbh1 + kt, lBh1);
    gload16(pbl0 + kt, lBl0);
    gload16(pbl1 + kt, lBl1);
    __syncthreads();           // drains vmcnt+lgkmcnt: tiles resident

    f16x8 ah[4], al[4], bh[4], bl[4];
#pragma unroll
    for (int i = 0; i < 4; ++i) {
      ah[i] = *reinterpret_cast<const f16x8*>(arh + i * 512);
      al[i] = *reinterpret_cast<const f16x8*>(arl + i * 512);
      bh[i] = *reinterpret_cast<const f16x8*>(brh + i * 512);
      bl[i] = *reinterpret_cast<const f16x8*>(brl + i * 512);
    }
#pragma unroll
    for (int mi = 0; mi < 4; ++mi)
#pragma unroll
      for (int ni = 0; ni < 4; ++ni) {
        acc[mi][ni] = __builtin_amdgcn_mfma_f32_16x16x32_f16(ah[mi], bh[ni], acc[mi][ni], 0, 0, 0);
        acc[mi][ni] = __builtin_amdgcn_mfma_f32_16x16x32_f16(al[mi], bh[ni], acc[mi][ni], 0, 0, 0);
        acc[mi][ni] = __builtin_amdgcn_mfma_f32_16x16x32_f16(ah[mi], bl[ni], acc[mi][ni], 0, 0, 0);
      }
    __syncthreads();           // all reads done before next stage overwrites
  }

  // C/D layout: col = lane&15, row = (lane>>4)*4 + reg   [m89, dtype-independent]
  int crow0 = brow + wrow + (kb << 2);
  int ccol0 = bcol + wcol + lr;
#pragma unroll
  for (int ni = 0; ni < 4; ++ni) {
    int col = ccol0 + (ni << 4);
    float bv = bias ? bias[col] : 0.0f;
#pragma unroll
    for (int mi = 0; mi < 4; ++mi) {
#pragma unroll
      for (int r = 0; r < 4; ++r) {
        int row = crow0 + (mi << 4) + r;
        C[(size_t)row * ldc + col] = acc[mi][ni][r] + bv;
      }
    }
  }
}

// ---------------- group attention on one slice: one wave per (b,g,h) -----------
// lane = j*16 + tq : j = row-in-group (0..3), tq = d-quarter (0..15)
// O overwrites q-region in place (unit owns rows [4grp,4grp+4) x cols [64h,64h+64))
__global__ void attn_kernel(float* __restrict__ qkv) {
  int u    = (blockIdx.x << 2) + (threadIdx.x >> 6);   // Ms*4 units per slice
  int lane = threadIdx.x & 63;
  int j  = lane >> 4;
  int tq = lane & 15;
  int h   = u & 15;
  int grp = u >> 4;
  size_t row = (size_t)grp * 4 + j;
  size_t idx = row * 3072 + h * 64 + (tq << 2);

  f32x4 qv = *reinterpret_cast<const f32x4*>(qkv + idx);          // q
  f32x4 kv = *reinterpret_cast<const f32x4*>(qkv + idx + 1024);   // k
  f32x4 vv = *reinterpret_cast<const f32x4*>(qkv + idx + 2048);   // v
  qv *= 0.125f;   // Dh^-0.5

  float s[4];
#pragma unroll
  for (int e = 0; e < 4; ++e) {          // score vs key row m = j ^ e
    f32x4 ke;
    if (e == 0) ke = kv;
    else {
#pragma unroll
      for (int c = 0; c < 4; ++c) ke[c] = __shfl_xor(kv[c], e << 4);
    }
    float p = qv[0]*ke[0] + qv[1]*ke[1] + qv[2]*ke[2] + qv[3]*ke[3];
    p += __shfl_xor(p, 1);
    p += __shfl_xor(p, 2);
    p += __shfl_xor(p, 4);
    p += __shfl_xor(p, 8);               // 16-lane j-group holds the full dot
    s[e] = p;
  }
  float mx = fmaxf(fmaxf(s[0], s[1]), fmaxf(s[2], s[3]));
  float e0 = expf(s[0] - mx), e1 = expf(s[1] - mx), e2 = expf(s[2] - mx), e3 = expf(s[3] - mx);
  float inv = 1.0f / (e0 + e1 + e2 + e3);
  float P[4] = {e0 * inv, e1 * inv, e2 * inv, e3 * inv};

  f32x4 o = {0.0f, 0.0f, 0.0f, 0.0f};
#pragma unroll
  for (int e = 0; e < 4; ++e) {
    f32x4 ve;
    if (e == 0) ve = vv;
    else {
#pragma unroll
      for (int c = 0; c < 4; ++c) ve[c] = __shfl_xor(vv[c], e << 4);
    }
    o += P[e] * ve;
  }

  *reinterpret_cast<f32x4*>(qkv + idx) = o;   // in-place over q
}

// ---------------- launch ----------------
extern "C" void kernel_launch(void* const* d_in, const int* in_sizes, int n_in,
                              void* d_out, int out_size, void* d_ws, size_t ws_size,
                              hipStream_t stream) {
  const float* x      = (const float*)d_in[0];
  const float* w_qkv  = (const float*)d_in[1];
  const float* w_proj = (const float*)d_in[2];
  const float* b_proj = (const float*)d_in[3];
  float* out = (float*)d_out;
  char* ws = (char*)d_ws;

  // tier selection: Ms rows per slice so ws fits (all tiers f32-accurate)
  int Ms;
  if      (ws_size >= 117440512ull) Ms = 8192;   // 112 MiB
  else if (ws_size >=  41943040ull) Ms = 2048;   //  40 MiB
  else                              Ms = 512;    //  22 MiB
  const int SL = 32768 / Ms;

  size_t qkvBytes = (size_t)Ms * 3072 * 4;
  float*    QKVs = (float*)ws;
  _Float16* Bqh  = (_Float16*)(ws + qkvBytes);
  _Float16* Bql  = (_Float16*)(ws + qkvBytes + 6291456ull);
  _Float16* Bph  = (_Float16*)(ws + qkvBytes + 12582912ull);
  _Float16* Bpl  = (_Float16*)(ws + qkvBytes + 14680064ull);

  wsplit_kernel<<<dim3(48, 16), 256, 0, stream>>>(w_qkv, Bqh, Bql, 3072);
  wsplit_kernel<<<dim3(16, 16), 256, 0, stream>>>(w_proj, Bph, Bpl, 1024);

  for (int s = 0; s < SL; ++s) {
    const float* xs = x + (size_t)s * Ms * 1024;
    // GEMM1: grid = (Ms/128)*(3072/128) blocks — multiple of 8 for all tiers
    gemm_split_kernel<<<(Ms >> 7) * 24, 256, 0, stream>>>(
        xs, Bqh, Bql, QKVs, nullptr, Ms, 3072, 1024, 3072);
    // attn: Ms*4 units, 4 units (waves) per block
    attn_kernel<<<Ms, 256, 0, stream>>>(QKVs);
    // GEMM2: A = q-region (lda=3072)
    gemm_split_kernel<<<(Ms >> 7) * 8, 256, 0, stream>>>(
        QKVs, Bph, Bpl, out + (size_t)s * Ms * 1024, b_proj, Ms, 1024, 3072, 1024);
  }
}